// Round 2
// baseline (20832.770 us; speedup 1.0000x reference)
//
#include <hip/hip_runtime.h>

typedef unsigned short ushort_t;
typedef unsigned int uint_t;
typedef __attribute__((ext_vector_type(8))) short bf16x8;
typedef __attribute__((ext_vector_type(4))) float f32x4;

__device__ __forceinline__ ushort_t f2bf(float f) {
  unsigned u = __float_as_uint(f);
  unsigned r = (u + 0x7fffu + ((u >> 16) & 1u)) >> 16;
  return (ushort_t)r;
}
__device__ __forceinline__ float bf2f(ushort_t h) {
  return __uint_as_float(((unsigned)h) << 16);
}

#if defined(__has_builtin)
#if __has_builtin(__builtin_amdgcn_global_load_lds)
#define USE_GLL 1
#endif
#endif
#ifndef USE_GLL
#define USE_GLL 0
#endif

__device__ __forceinline__ void gll16(const void* g, void* l) {
#if USE_GLL
  __builtin_amdgcn_global_load_lds(
      (const __attribute__((address_space(1))) unsigned int*)g,
      (__attribute__((address_space(3))) unsigned int*)l, 16, 0, 0);
#endif
}

// ---------------- fp32 -> bf16 convert (grid-stride, float4) ----------------
__global__ void k_cvt_bf16(const float* __restrict__ in, ushort_t* __restrict__ out, int n4) {
  int i = blockIdx.x * blockDim.x + threadIdx.x;
  int stride = gridDim.x * blockDim.x;
  for (; i < n4; i += stride) {
    float4 v = reinterpret_cast<const float4*>(in)[i];
    ushort4 o;
    o.x = f2bf(v.x); o.y = f2bf(v.y); o.z = f2bf(v.z); o.w = f2bf(v.w);
    reinterpret_cast<ushort4*>(out)[i] = o;
  }
}

// ---------------- zero init (u32) ----------------
__global__ void k_zero(uint_t* __restrict__ p, int n) {
  int i = blockIdx.x * blockDim.x + threadIdx.x;
  if (i < n) p[i] = 0u;
}

// ------------- 512x512 transpose + convert: out[n][k] = bf16(in[k][n]) ------
__global__ __launch_bounds__(256) void k_transpose_cvt(const float* __restrict__ in,
                                                       ushort_t* __restrict__ out) {
  __shared__ float tile[32][33];
  int bx = blockIdx.x & 15, by = blockIdx.x >> 4;
  int tx = threadIdx.x & 31, ty = threadIdx.x >> 5;  // ty in 0..7
#pragma unroll
  for (int i = 0; i < 4; ++i)
    tile[ty + i * 8][tx] = in[(size_t)(by * 32 + ty + i * 8) * 512 + bx * 32 + tx];
  __syncthreads();
#pragma unroll
  for (int i = 0; i < 4; ++i)
    out[(size_t)(bx * 32 + ty + i * 8) * 512 + by * 32 + tx] = f2bf(tile[tx][ty + i * 8]);
}

// ---------------- bf16 MFMA GEMM: C[M][N] = A[M][K] * Bt[N][K]^T + bias -----
#define BM 128
#define BN 128
#define BK 32

template <int OUT_BF16>
__global__ __launch_bounds__(256, 2) void k_gemm(const ushort_t* __restrict__ A,
                                                 const ushort_t* __restrict__ Bt,
                                                 const float* __restrict__ bias,
                                                 void* __restrict__ Cout,
                                                 int M, int N, int K) {
  __shared__ __align__(16) ushort_t As[2][BM][BK];
  __shared__ __align__(16) ushort_t Bs[2][BN][BK];

  const int tid = threadIdx.x;
  const int w = tid >> 6;       // wave 0..3
  const int l = tid & 63;       // lane
  const int nbn = N / BN;
  const int bm0 = (int)(blockIdx.x / nbn) * BM;
  const int bn0 = (int)(blockIdx.x % nbn) * BN;
  const int wm = w >> 1, wn = w & 1;

  auto stage = [&](int buf, int kt) {
#pragma unroll
    for (int c = 0; c < 2; ++c) {
      const int row = c * 64 + w * 16 + (l >> 2);
      const int ke = kt + (l & 3) * 8;
#if USE_GLL
      gll16(A + (size_t)(bm0 + row) * K + ke, &As[buf][c * 64 + w * 16][0]);
      gll16(Bt + (size_t)(bn0 + row) * K + ke, &Bs[buf][c * 64 + w * 16][0]);
#else
      *(bf16x8*)&As[buf][row][(l & 3) * 8] = *(const bf16x8*)(A + (size_t)(bm0 + row) * K + ke);
      *(bf16x8*)&Bs[buf][row][(l & 3) * 8] = *(const bf16x8*)(Bt + (size_t)(bn0 + row) * K + ke);
#endif
    }
  };

  f32x4 acc[4][4] = {};
  const int nkt = K / BK;
  stage(0, 0);
  int cur = 0;
  for (int kt = 0; kt < nkt; ++kt) {
    __syncthreads();
    if (kt + 1 < nkt) stage(cur ^ 1, (kt + 1) * BK);
    bf16x8 af[4], bfr[4];
#pragma unroll
    for (int m = 0; m < 4; ++m)
      af[m] = *(const bf16x8*)&As[cur][wm * 64 + m * 16 + (l & 15)][(l >> 4) * 8];
#pragma unroll
    for (int n = 0; n < 4; ++n)
      bfr[n] = *(const bf16x8*)&Bs[cur][wn * 64 + n * 16 + (l & 15)][(l >> 4) * 8];
#pragma unroll
    for (int m = 0; m < 4; ++m)
#pragma unroll
      for (int n = 0; n < 4; ++n)
        acc[m][n] = __builtin_amdgcn_mfma_f32_16x16x32_bf16(af[m], bfr[n], acc[m][n], 0, 0, 0);
    cur ^= 1;
  }

  const int r0 = bm0 + wm * 64, c0 = bn0 + wn * 64;
#pragma unroll
  for (int n = 0; n < 4; ++n) {
    const int cc = c0 + n * 16 + (l & 15);
    const float bv = bias[cc];
#pragma unroll
    for (int m = 0; m < 4; ++m) {
      const int rr = r0 + m * 16 + ((l >> 4) << 2);
#pragma unroll
      for (int j = 0; j < 4; ++j) {
        float v = acc[m][n][j] + bv;
        if (OUT_BF16)
          ((ushort_t*)Cout)[(size_t)(rr + j) * N + cc] = f2bf(v);
        else
          ((float*)Cout)[(size_t)(rr + j) * N + cc] = v;
      }
    }
  }
}

// ---------------- RNN scan: register-resident W_hh slices + MFMA ------------
// 64 WGs = 16 sets (4 batches each) x 4 column-slices (128 cols each).
// 512 threads = 8 waves; wave w owns 16 columns => W frags = 16 x bf16x8 = 64 VGPR.
// h exchanged per step via global hx[set][buf][4][512] packed (bf16 hi<<16 | lo),
// synchronized with per-set monotone counters (fence + device-scope atomics).
#define SCAN_T 1024

__global__ __launch_bounds__(512) void k_scan_mfma(
    const ushort_t* __restrict__ xw,    // [64][T][512] bf16
    const ushort_t* __restrict__ WhhT,  // [512(j)][512(k)] bf16 (W_hh transposed)
    ushort_t* __restrict__ hs,          // [64][T][512] bf16 (out)
    float* __restrict__ h_last,         // [64][512] f32 (out)
    uint_t* __restrict__ hx,            // [16][2][4][512] u32 packed
    uint_t* __restrict__ cnt) {         // [16] stride-64 counters
  const int tid = threadIdx.x;
  const int w = tid >> 6, l = tid & 63;
  const int s = blockIdx.x >> 2;              // set 0..15
  const int g = blockIdx.x & 3;               // slice 0..3
  const int col = g * 128 + w * 16 + (l & 15);  // this lane's j-column
  const int r = l & 3;                        // A-row (batch) for frag reads
  const int h4 = l >> 4;                      // k-subgroup 0..3
  const int b0 = s * 4;                       // global batch base

  // LDS A staging, row stride 528 ushorts (1056B) -> 2-way max bank aliasing
  __shared__ __align__(16) ushort_t lhi[4 * 528];
  __shared__ __align__(16) ushort_t llo[4 * 528];

  // persistent W B-frags: wb[kt][lane] = WhhT[col][kt*32 + h4*8 + e]
  bf16x8 wb[16];
  {
    const ushort_t* wrow = WhhT + (size_t)col * 512 + h4 * 8;
#pragma unroll
    for (int kt = 0; kt < 16; ++kt)
      wb[kt] = *(const bf16x8*)(wrow + kt * 32);
  }

  uint_t* const hxs = hx + (size_t)s * 4096;
  uint_t* const cptr = cnt + s * 64;

  // xw prefetch for t=0
  ushort_t xwn[4];
  if (l < 16) {
#pragma unroll
    for (int b = 0; b < 4; ++b)
      xwn[b] = xw[(size_t)(b0 + b) * SCAN_T * 512 + col];
  }
  float hlast[4] = {0.f, 0.f, 0.f, 0.f};

  for (int t = 0; t < SCAN_T; ++t) {
    // promote prefetched xw; issue prefetch for t+1 (hidden behind spin+MFMA)
    float xwc[4];
    if (l < 16) {
#pragma unroll
      for (int b = 0; b < 4; ++b) xwc[b] = bf2f(xwn[b]);
      const int tn = (t + 1 < SCAN_T) ? t + 1 : t;
#pragma unroll
      for (int b = 0; b < 4; ++b)
        xwn[b] = xw[((size_t)(b0 + b) * SCAN_T + tn) * 512 + col];
    }

    // wait until all 4 WGs of this set finished step t-1
    if (tid == 0) {
      const uint_t need = 4u * (uint_t)t;
      while (__hip_atomic_load(cptr, __ATOMIC_RELAXED, __HIP_MEMORY_SCOPE_AGENT) < need)
        __builtin_amdgcn_s_sleep(1);
    }
    __syncthreads();   // join spin result; also protects LDS reuse across iters
    __threadfence();   // acquire: invalidate so hx reads see remote writes

    // stage hx -> LDS hi/lo planes (512 threads x 16B, coalesced)
    {
      const uint4 p = *(const uint4*)(hxs + (t & 1) * 2048 + tid * 4);
      const int b = tid >> 7, k4 = (tid & 127) * 4;
      ushort4 hi4, lo4;
      hi4.x = (ushort_t)(p.x >> 16); lo4.x = (ushort_t)(p.x & 0xffffu);
      hi4.y = (ushort_t)(p.y >> 16); lo4.y = (ushort_t)(p.y & 0xffffu);
      hi4.z = (ushort_t)(p.z >> 16); lo4.z = (ushort_t)(p.z & 0xffffu);
      hi4.w = (ushort_t)(p.w >> 16); lo4.w = (ushort_t)(p.w & 0xffffu);
      *(ushort4*)&lhi[b * 528 + k4] = hi4;
      *(ushort4*)&llo[b * 528 + k4] = lo4;
    }
    __syncthreads();

    // MFMA: C[row=batch][col] = sum_k (hi+lo)[batch][k] * W[k][col]
    f32x4 acc = {0.f, 0.f, 0.f, 0.f};
#pragma unroll
    for (int kt = 0; kt < 16; ++kt) {
      const int ao = r * 528 + kt * 32 + h4 * 8;
      bf16x8 ah = *(const bf16x8*)&lhi[ao];
      bf16x8 al = *(const bf16x8*)&llo[ao];
      acc = __builtin_amdgcn_mfma_f32_16x16x32_bf16(ah, wb[kt], acc, 0, 0, 0);
      acc = __builtin_amdgcn_mfma_f32_16x16x32_bf16(al, wb[kt], acc, 0, 0, 0);
    }

    // epilogue: lanes l<16 hold C rows 0..3 (the 4 batches) at column `col`
    if (l < 16) {
#pragma unroll
      for (int b = 0; b < 4; ++b) {
        float hv = tanhf(acc[b] + xwc[b]);
        hlast[b] = hv;
        ushort_t hi = f2bf(hv);
        ushort_t lo = f2bf(hv - bf2f(hi));
        __builtin_nontemporal_store(hi, hs + ((size_t)(b0 + b) * SCAN_T + t) * 512 + col);
        hxs[((t + 1) & 1) * 2048 + b * 512 + col] = ((uint_t)hi << 16) | (uint_t)lo;
      }
    }
    __threadfence();   // release: flush hx to device-coherent point
    __syncthreads();   // all threads' stores+fences complete
    if (tid == 0)
      __hip_atomic_fetch_add(cptr, 1u, __ATOMIC_RELAXED, __HIP_MEMORY_SCOPE_AGENT);
  }

  if (l < 16) {
#pragma unroll
    for (int b = 0; b < 4; ++b)
      h_last[(size_t)(b0 + b) * 512 + col] = hlast[b];
  }
}

// ---------------------------------------------------------------------------
extern "C" void kernel_launch(void* const* d_in, const int* in_sizes, int n_in,
                              void* d_out, int out_size, void* d_ws, size_t ws_size,
                              hipStream_t stream) {
  const float* x    = (const float*)d_in[0];  // [64][1024][512]
  const float* W_xh = (const float*)d_in[1];  // [512][512]
  const float* b_h  = (const float*)d_in[2];  // [512]
  const float* W_hh = (const float*)d_in[3];  // [512][512]
  const float* W_o  = (const float*)d_in[4];  // [512][512]
  const float* b_o  = (const float*)d_in[5];  // [512]
  float* out = (float*)d_out;                 // logits [64][1024][512] ++ h_last [64][512]

  const size_t XWN = (size_t)64 * 1024 * 512;
  char* ws = (char*)d_ws;
  ushort_t* xbf  = (ushort_t*)(ws);                      // 64 MiB (x bf16 -> later hs)
  ushort_t* xwbf = (ushort_t*)(ws + XWN * 2);            // 64 MiB (xW bf16)
  ushort_t* WxhT = (ushort_t*)(ws + XWN * 4);            // 512 KiB
  // This 512 KiB slot is hx+cnt during the scan, then W_o^T after the scan:
  char*     slot = (char*)(ws + XWN * 4 + 524288);
  uint_t*   hx   = (uint_t*)slot;                        // 256 KiB
  uint_t*   cnt  = (uint_t*)(slot + 262144);             // 4 KiB
  ushort_t* WoT  = (ushort_t*)slot;                      // 512 KiB (after scan)
  ushort_t* WhhT = (ushort_t*)(ws + XWN * 4 + 1048576);  // 512 KiB

  // prep: converts + transposes + sync-state zeroing
  k_cvt_bf16<<<4096, 256, 0, stream>>>(x, xbf, (int)(XWN / 4));
  k_transpose_cvt<<<256, 256, 0, stream>>>(W_xh, WxhT);
  k_transpose_cvt<<<256, 256, 0, stream>>>(W_hh, WhhT);
  k_zero<<<132, 512, 0, stream>>>(hx, 65536 + 1024);

  // xW = x @ W_xh + b_h   (bf16 out)
  k_gemm<1><<<2048, 256, 0, stream>>>(xbf, WxhT, b_h, xwbf, 65536, 512, 512);

  // sequential scan: writes hs (bf16, reusing x's buffer) and h_last (f32)
  k_scan_mfma<<<64, 512, 0, stream>>>(xwbf, WhhT, xbf, out + XWN, hx, cnt);

  // W_o^T now overwrites the hx/cnt slot (scan is done)
  k_transpose_cvt<<<256, 256, 0, stream>>>(W_o, WoT);

  // logits = hs @ W_o + b_o   (f32 out)
  k_gemm<0><<<2048, 256, 0, stream>>>(xbf, WoT, b_o, out, 65536, 512, 512);
}

// Round 3
// 4482.187 us; speedup vs baseline: 4.6479x; 4.6479x over previous
//
#include <hip/hip_runtime.h>

typedef _Float16 f16;
typedef __attribute__((ext_vector_type(4))) _Float16 f16x4;
typedef __attribute__((ext_vector_type(8))) _Float16 f16x8;
typedef __attribute__((ext_vector_type(4))) float f32x4;

__device__ __forceinline__ float tanh_fast(float x) {
  // tanh(x) = 1 - 2/(exp(2x)+1); exp inf/0 endpoints give exact +-1
  float e = __expf(2.0f * x);
  return 1.0f - 2.0f / (e + 1.0f);
}

#if defined(__has_builtin)
#if __has_builtin(__builtin_amdgcn_global_load_lds)
#define USE_GLL 1
#endif
#endif
#ifndef USE_GLL
#define USE_GLL 0
#endif

__device__ __forceinline__ void gll16(const void* g, void* l) {
#if USE_GLL
  __builtin_amdgcn_global_load_lds(
      (const __attribute__((address_space(1))) unsigned int*)g,
      (__attribute__((address_space(3))) unsigned int*)l, 16, 0, 0);
#endif
}

// ---------------- fp32 -> fp16 convert (grid-stride, float4) ----------------
__global__ void k_cvt_f16(const float* __restrict__ in, f16* __restrict__ out, int n4) {
  int i = blockIdx.x * blockDim.x + threadIdx.x;
  int stride = gridDim.x * blockDim.x;
  for (; i < n4; i += stride) {
    float4 v = reinterpret_cast<const float4*>(in)[i];
    f16x4 o;
    o[0] = (f16)v.x; o[1] = (f16)v.y; o[2] = (f16)v.z; o[3] = (f16)v.w;
    *reinterpret_cast<f16x4*>(out + (size_t)i * 4) = o;
  }
}

// ------------- 512x512 transpose + convert: out[n][k] = f16(in[k][n]) -------
__global__ __launch_bounds__(256) void k_transpose_cvt(const float* __restrict__ in,
                                                       f16* __restrict__ out) {
  __shared__ float tile[32][33];
  int bx = blockIdx.x & 15, by = blockIdx.x >> 4;
  int tx = threadIdx.x & 31, ty = threadIdx.x >> 5;  // ty in 0..7
#pragma unroll
  for (int i = 0; i < 4; ++i)
    tile[ty + i * 8][tx] = in[(size_t)(by * 32 + ty + i * 8) * 512 + bx * 32 + tx];
  __syncthreads();
#pragma unroll
  for (int i = 0; i < 4; ++i)
    out[(size_t)(bx * 32 + ty + i * 8) * 512 + by * 32 + tx] = (f16)tile[tx][ty + i * 8];
}

// --------- W_hh frag-pack: Wf[cb][kt][q][c][e] = f16(W_hh[kt*32+q*8+e][cb*16+c])
__global__ __launch_bounds__(256) void k_packW(const float* __restrict__ Whh,
                                               f16* __restrict__ Wf) {
  int id = blockIdx.x * 256 + threadIdx.x;  // 0..32767, one 16B block each
  int c = id & 15, q = (id >> 4) & 3, kt = (id >> 6) & 15, cb = id >> 10;
  f16x8 blk;
#pragma unroll
  for (int e = 0; e < 8; ++e)
    blk[e] = (f16)Whh[(size_t)(kt * 32 + q * 8 + e) * 512 + cb * 16 + c];
  reinterpret_cast<f16x8*>(Wf)[id] = blk;
}

// ---------------- fp16 MFMA GEMM: C[M][N] = A[M][K] * Bt[N][K]^T + bias -----
#define BM 128
#define BN 128
#define BK 32

template <int OUT_F16>
__global__ __launch_bounds__(256, 2) void k_gemm(const f16* __restrict__ A,
                                                 const f16* __restrict__ Bt,
                                                 const float* __restrict__ bias,
                                                 void* __restrict__ Cout,
                                                 int M, int N, int K) {
  __shared__ __align__(16) f16 As[2][BM][BK];
  __shared__ __align__(16) f16 Bs[2][BN][BK];

  const int tid = threadIdx.x;
  const int w = tid >> 6;  // wave 0..3
  const int l = tid & 63;  // lane
  const int nbn = N / BN;
  const int bm0 = (int)(blockIdx.x / nbn) * BM;
  const int bn0 = (int)(blockIdx.x % nbn) * BN;
  const int wm = w >> 1, wn = w & 1;

  auto stage = [&](int buf, int kt) {
#pragma unroll
    for (int c = 0; c < 2; ++c) {
      const int row = c * 64 + w * 16 + (l >> 2);
      const int ke = kt + (l & 3) * 8;
#if USE_GLL
      gll16(A + (size_t)(bm0 + row) * K + ke, &As[buf][c * 64 + w * 16][0]);
      gll16(Bt + (size_t)(bn0 + row) * K + ke, &Bs[buf][c * 64 + w * 16][0]);
#else
      *(f16x8*)&As[buf][row][(l & 3) * 8] = *(const f16x8*)(A + (size_t)(bm0 + row) * K + ke);
      *(f16x8*)&Bs[buf][row][(l & 3) * 8] = *(const f16x8*)(Bt + (size_t)(bn0 + row) * K + ke);
#endif
    }
  };

  f32x4 acc[4][4] = {};
  const int nkt = K / BK;
  stage(0, 0);
  int cur = 0;
  for (int kt = 0; kt < nkt; ++kt) {
    __syncthreads();
    if (kt + 1 < nkt) stage(cur ^ 1, (kt + 1) * BK);
    f16x8 af[4], bfr[4];
#pragma unroll
    for (int m = 0; m < 4; ++m)
      af[m] = *(const f16x8*)&As[cur][wm * 64 + m * 16 + (l & 15)][(l >> 4) * 8];
#pragma unroll
    for (int n = 0; n < 4; ++n)
      bfr[n] = *(const f16x8*)&Bs[cur][wn * 64 + n * 16 + (l & 15)][(l >> 4) * 8];
#pragma unroll
    for (int m = 0; m < 4; ++m)
#pragma unroll
      for (int n = 0; n < 4; ++n)
        acc[m][n] = __builtin_amdgcn_mfma_f32_16x16x32_f16(af[m], bfr[n], acc[m][n], 0, 0, 0);
    cur ^= 1;
  }

  // Epilogue. C/D layout: col = lane&15, row = (lane>>4)*4 + j  [HW-verified]
  const int r0 = bm0 + wm * 64, c0 = bn0 + wn * 64;
#pragma unroll
  for (int n = 0; n < 4; ++n) {
    const int cc = c0 + n * 16 + (l & 15);
    const float bv = bias[cc];
#pragma unroll
    for (int m = 0; m < 4; ++m) {
      const int rr = r0 + m * 16 + ((l >> 4) << 2);
#pragma unroll
      for (int j = 0; j < 4; ++j) {
        float v = acc[m][n][j] + bv;
        if (OUT_F16)
          ((f16*)Cout)[(size_t)(rr + j) * N + cc] = (f16)v;
        else
          ((float*)Cout)[(size_t)(rr + j) * N + cc] = v;
      }
    }
  }
}

// ---------------- RNN scan: W resident on ONE CU per 16-batch set -----------
// 4 WGs x 1024 threads (16 waves). Wave w owns col-blocks cbA=w (16 cols,
// register-resident frags: 64 VGPR) and cbB=16+w (w<6: LDS-resident 96KB;
// w>=6: streamed from L2, 16KB/step/wave). h (16x512 fp16) lives in LDS;
// the only per-step sync is two __syncthreads. No atomics, no fences.
#define SCAN_T 1024

__global__ __launch_bounds__(1024, 4) void k_scan_res(
    const f16* __restrict__ xw,   // [64][T][512]
    const f16* __restrict__ Wf,   // frag-packed [32][16][4][16][8]
    f16* __restrict__ hs,         // [64][T][512] (out)
    float* __restrict__ h_last) { // [64][512] (out)
  const int tid = threadIdx.x;
  const int w = tid >> 6, l = tid & 63;
  const int q = l >> 4, c = l & 15;
  const int b0 = blockIdx.x * 16;  // batch base of this set

  __shared__ __align__(16) f16 wlds[6][16][4][16][8];  // 96 KiB
  __shared__ __align__(16) f16 hplane[16][520];        // 16.25 KiB (stride 520: conflict-free frag reads)

  const int cbA = w;
  const int cbB = 16 + w;
  const bool isLds = (w < 6);

  const f16x8* WfB = reinterpret_cast<const f16x8*>(Wf);

  // register-resident frags for cbA
  f16x8 wa[16];
#pragma unroll
  for (int kt = 0; kt < 16; ++kt)
    wa[kt] = WfB[((cbA * 16 + kt) * 4 + q) * 16 + c];

  // stage LDS-resident cbs 16..21 (6144 16B blocks, coalesced)
  for (int i = tid; i < 6 * 16 * 4 * 16; i += 1024)
    reinterpret_cast<f16x8*>(wlds)[i] = WfB[16 * 1024 + i];

  // h0 = 0
  for (int i = tid; i < 16 * 520; i += 1024) hplane[0][i] = (f16)0.0f;
  __syncthreads();

  // stream base for cbB (w>=6): +kt*64 blocks walks kt
  const f16x8* strm = WfB + (size_t)cbB * 1024 + q * 16 + c;

  const int r0j = q * 4;  // this lane's 4 output rows (batches r0j..r0j+3)

  for (int t = 0; t < SCAN_T; ++t) {
    // xw for this step (independent loads; scheduled under the MFMA block)
    f16 xwv[8];
#pragma unroll
    for (int j = 0; j < 4; ++j) {
      xwv[j]     = xw[((size_t)(b0 + r0j + j) * SCAN_T + t) * 512 + cbA * 16 + c];
      xwv[4 + j] = xw[((size_t)(b0 + r0j + j) * SCAN_T + t) * 512 + cbB * 16 + c];
    }

    f32x4 accA = {0.f, 0.f, 0.f, 0.f}, accB = {0.f, 0.f, 0.f, 0.f};
    f16x8 s0, s1;
    if (!isLds) { s0 = strm[0]; s1 = strm[64]; }
#pragma unroll
    for (int kt = 0; kt < 16; ++kt) {
      // A-frag: row = l&15 (batch), k = kt*32 + q*8 + e   [layout HW-verified]
      f16x8 af = *(const f16x8*)&hplane[c][kt * 32 + q * 8];
      accA = __builtin_amdgcn_mfma_f32_16x16x32_f16(af, wa[kt], accA, 0, 0, 0);
      f16x8 wb;
      if (isLds) {
        wb = *(const f16x8*)&wlds[w][kt][q][c][0];
      } else {
        wb = s0; s0 = s1;
        if (kt + 2 < 16) s1 = strm[(size_t)(kt + 2) * 64];
      }
      accB = __builtin_amdgcn_mfma_f32_16x16x32_f16(af, wb, accB, 0, 0, 0);
    }
    __syncthreads();  // all A-frag reads of h(t) complete

    // epilogue: lane holds C rows r0j..r0j+3 at cols cbA*16+c and cbB*16+c
#pragma unroll
    for (int j = 0; j < 4; ++j) {
      const int row = r0j + j;
      float vA = tanh_fast(accA[j] + (float)xwv[j]);
      float vB = tanh_fast(accB[j] + (float)xwv[4 + j]);
      hplane[row][cbA * 16 + c] = (f16)vA;
      hplane[row][cbB * 16 + c] = (f16)vB;
      hs[((size_t)(b0 + row) * SCAN_T + t) * 512 + cbA * 16 + c] = (f16)vA;
      hs[((size_t)(b0 + row) * SCAN_T + t) * 512 + cbB * 16 + c] = (f16)vB;
      if (t == SCAN_T - 1) {
        h_last[(size_t)(b0 + row) * 512 + cbA * 16 + c] = vA;
        h_last[(size_t)(b0 + row) * 512 + cbB * 16 + c] = vB;
      }
    }
    __syncthreads();  // h(t+1) visible to all before next step
  }
}

// ---------------------------------------------------------------------------
extern "C" void kernel_launch(void* const* d_in, const int* in_sizes, int n_in,
                              void* d_out, int out_size, void* d_ws, size_t ws_size,
                              hipStream_t stream) {
  const float* x    = (const float*)d_in[0];  // [64][1024][512]
  const float* W_xh = (const float*)d_in[1];  // [512][512]
  const float* b_h  = (const float*)d_in[2];  // [512]
  const float* W_hh = (const float*)d_in[3];  // [512][512]
  const float* W_o  = (const float*)d_in[4];  // [512][512]
  const float* b_o  = (const float*)d_in[5];  // [512]
  float* out = (float*)d_out;                 // logits [64][1024][512] ++ h_last [64][512]

  const size_t XWN = (size_t)64 * 1024 * 512;
  char* ws = (char*)d_ws;
  f16* xf   = (f16*)(ws);                       // 64 MiB (x f16 -> later hs)
  f16* xwf  = (f16*)(ws + XWN * 2);             // 64 MiB (xW f16)
  f16* WxhT = (f16*)(ws + XWN * 4);             // 512 KiB
  f16* WoT  = (f16*)(ws + XWN * 4 + 524288);    // 512 KiB
  f16* Wf   = (f16*)(ws + XWN * 4 + 1048576);   // 512 KiB (frag-packed W_hh)

  // prep: converts + transposes + frag-pack
  k_cvt_f16<<<4096, 256, 0, stream>>>(x, xf, (int)(XWN / 4));
  k_transpose_cvt<<<256, 256, 0, stream>>>(W_xh, WxhT);
  k_transpose_cvt<<<256, 256, 0, stream>>>(W_o, WoT);
  k_packW<<<128, 256, 0, stream>>>(W_hh, Wf);

  // xW = x @ W_xh + b_h   (f16 out)
  k_gemm<1><<<2048, 256, 0, stream>>>(xf, WxhT, b_h, xwf, 65536, 512, 512);

  // sequential scan: 4 self-contained WGs, no cross-WG communication
  k_scan_res<<<4, 1024, 0, stream>>>(xwf, Wf, xf, out + XWN);

  // logits = hs @ W_o + b_o   (f32 out)
  k_gemm<0><<<2048, 256, 0, stream>>>(xf, WoT, b_o, out, 65536, 512, 512);
}

// Round 4
// 2793.374 us; speedup vs baseline: 7.4579x; 1.6046x over previous
//
#include <hip/hip_runtime.h>

typedef _Float16 f16;
typedef __attribute__((ext_vector_type(4))) _Float16 f16x4;
typedef __attribute__((ext_vector_type(8))) _Float16 f16x8;
typedef __attribute__((ext_vector_type(4))) float f32x4;

__device__ __forceinline__ float tanh_fast(float x) {
  // tanh(x) = 1 - 2/(exp(2x)+1); hw exp + hw rcp (endpoints exact)
  float e = __expf(2.0f * x);
  return 1.0f - 2.0f * __builtin_amdgcn_rcpf(e + 1.0f);
}

// raw LDS-only workgroup sync: no vmcnt drain (keeps global prefetches alive)
__device__ __forceinline__ void wg_sync_lds() {
  asm volatile("s_waitcnt lgkmcnt(0)" ::: "memory");
  __builtin_amdgcn_sched_barrier(0);
  __builtin_amdgcn_s_barrier();
  __builtin_amdgcn_sched_barrier(0);
}

#if defined(__has_builtin)
#if __has_builtin(__builtin_amdgcn_global_load_lds)
#define USE_GLL 1
#endif
#endif
#ifndef USE_GLL
#define USE_GLL 0
#endif

__device__ __forceinline__ void gll16(const void* g, void* l) {
#if USE_GLL
  __builtin_amdgcn_global_load_lds(
      (const __attribute__((address_space(1))) unsigned int*)g,
      (__attribute__((address_space(3))) unsigned int*)l, 16, 0, 0);
#endif
}

// ---------------- fp32 -> fp16 convert (grid-stride, float4) ----------------
__global__ void k_cvt_f16(const float* __restrict__ in, f16* __restrict__ out, int n4) {
  int i = blockIdx.x * blockDim.x + threadIdx.x;
  int stride = gridDim.x * blockDim.x;
  for (; i < n4; i += stride) {
    float4 v = reinterpret_cast<const float4*>(in)[i];
    f16x4 o;
    o[0] = (f16)v.x; o[1] = (f16)v.y; o[2] = (f16)v.z; o[3] = (f16)v.w;
    *reinterpret_cast<f16x4*>(out + (size_t)i * 4) = o;
  }
}

// ------------- 512x512 transpose + convert: out[n][k] = f16(in[k][n]) -------
__global__ __launch_bounds__(256) void k_transpose_cvt(const float* __restrict__ in,
                                                       f16* __restrict__ out) {
  __shared__ float tile[32][33];
  int bx = blockIdx.x & 15, by = blockIdx.x >> 4;
  int tx = threadIdx.x & 31, ty = threadIdx.x >> 5;  // ty in 0..7
#pragma unroll
  for (int i = 0; i < 4; ++i)
    tile[ty + i * 8][tx] = in[(size_t)(by * 32 + ty + i * 8) * 512 + bx * 32 + tx];
  __syncthreads();
#pragma unroll
  for (int i = 0; i < 4; ++i)
    out[(size_t)(bx * 32 + ty + i * 8) * 512 + by * 32 + tx] = (f16)tile[tx][ty + i * 8];
}

// --------- W_hh frag-pack: Wf[cb][kt][q][c][e] = f16(W_hh[kt*32+q*8+e][cb*16+c])
__global__ __launch_bounds__(256) void k_packW(const float* __restrict__ Whh,
                                               f16* __restrict__ Wf) {
  int id = blockIdx.x * 256 + threadIdx.x;  // 0..32767, one 16B block each
  int c = id & 15, q = (id >> 4) & 3, kt = (id >> 6) & 15, cb = id >> 10;
  f16x8 blk;
#pragma unroll
  for (int e = 0; e < 8; ++e)
    blk[e] = (f16)Whh[(size_t)(kt * 32 + q * 8 + e) * 512 + cb * 16 + c];
  reinterpret_cast<f16x8*>(Wf)[id] = blk;
}

// ---------------- fp16 MFMA GEMM: C[M][N] = A[M][K] * Bt[N][K]^T + bias -----
// OUT: 0 = f32 linear, 2 = f16 packed-xw (scan-ready layout)
#define BM 128
#define BN 128
#define BK 32

template <int OUT>
__global__ __launch_bounds__(256, 2) void k_gemm(const f16* __restrict__ A,
                                                 const f16* __restrict__ Bt,
                                                 const float* __restrict__ bias,
                                                 void* __restrict__ Cout,
                                                 int M, int N, int K) {
  __shared__ __align__(16) f16 As[2][BM][BK];
  __shared__ __align__(16) f16 Bs[2][BN][BK];

  const int tid = threadIdx.x;
  const int w = tid >> 6;  // wave 0..3
  const int l = tid & 63;  // lane
  const int nbn = N / BN;
  const int bm0 = (int)(blockIdx.x / nbn) * BM;
  const int bn0 = (int)(blockIdx.x % nbn) * BN;
  const int wm = w >> 1, wn = w & 1;

  auto stage = [&](int buf, int kt) {
#pragma unroll
    for (int c = 0; c < 2; ++c) {
      const int row = c * 64 + w * 16 + (l >> 2);
      const int ke = kt + (l & 3) * 8;
#if USE_GLL
      gll16(A + (size_t)(bm0 + row) * K + ke, &As[buf][c * 64 + w * 16][0]);
      gll16(Bt + (size_t)(bn0 + row) * K + ke, &Bs[buf][c * 64 + w * 16][0]);
#else
      *(f16x8*)&As[buf][row][(l & 3) * 8] = *(const f16x8*)(A + (size_t)(bm0 + row) * K + ke);
      *(f16x8*)&Bs[buf][row][(l & 3) * 8] = *(const f16x8*)(Bt + (size_t)(bn0 + row) * K + ke);
#endif
    }
  };

  f32x4 acc[4][4] = {};
  const int nkt = K / BK;
  stage(0, 0);
  int cur = 0;
  for (int kt = 0; kt < nkt; ++kt) {
    __syncthreads();
    if (kt + 1 < nkt) stage(cur ^ 1, (kt + 1) * BK);
    f16x8 af[4], bfr[4];
#pragma unroll
    for (int m = 0; m < 4; ++m)
      af[m] = *(const f16x8*)&As[cur][wm * 64 + m * 16 + (l & 15)][(l >> 4) * 8];
#pragma unroll
    for (int n = 0; n < 4; ++n)
      bfr[n] = *(const f16x8*)&Bs[cur][wn * 64 + n * 16 + (l & 15)][(l >> 4) * 8];
#pragma unroll
    for (int m = 0; m < 4; ++m)
#pragma unroll
      for (int n = 0; n < 4; ++n)
        acc[m][n] = __builtin_amdgcn_mfma_f32_16x16x32_f16(af[m], bfr[n], acc[m][n], 0, 0, 0);
    cur ^= 1;
  }

  // Epilogue. C/D layout: col = lane&15, row = (lane>>4)*4 + j  [HW-verified]
  const int r0 = bm0 + wm * 64, c0 = bn0 + wn * 64;
#pragma unroll
  for (int n = 0; n < 4; ++n) {
    const int cc = c0 + n * 16 + (l & 15);
    const float bv = bias[cc];
#pragma unroll
    for (int m = 0; m < 4; ++m) {
      const int rr = r0 + m * 16 + ((l >> 4) << 2);
      if (OUT == 2) {
        // packed xw: element (Mrow=rr+j, cc), Mrow=(b<<10)|t
        // idx = ((((((set*256+tq)*8+w)*4+q)*4+j)*16+c)*16) + i*4 + ts, ts=j
        const int b = rr >> 10, trow = rr & 1023;
        const int set = b >> 4, qq = (b >> 2) & 3, jj = b & 3;
        const int cb = cc >> 4, ww = cb & 7, ii = cb >> 3, c2 = cc & 15;
        size_t idx =
            ((((((size_t)set * 256 + (trow >> 2)) * 8 + ww) * 4 + qq) * 4 + jj) * 16 + c2) * 16 +
            ii * 4;
        f16x4 pk;
#pragma unroll
        for (int j = 0; j < 4; ++j) pk[j] = (f16)(acc[m][n][j] + bv);
        *(f16x4*)((f16*)Cout + idx) = pk;
      } else {
#pragma unroll
        for (int j = 0; j < 4; ++j)
          ((float*)Cout)[(size_t)(rr + j) * N + cc] = acc[m][n][j] + bv;
      }
    }
  }
}

// ---------------- RNN scan: W resident on ONE CU per 16-batch set -----------
// 4 WGs x 512 threads (8 waves, 2/SIMD, 256-VGPR class). Wave w owns 4
// col-blocks: {w, 8+w} register-resident (128 VGPR), {16+w} LDS-resident
// (128 KiB), {24+w} streamed from L2 with a depth-4 rotating prefetch that
// wraps across steps. h lives in LDS in MFMA-frag layout (conflict-free
// b128 reads). Barriers are LDS-only (no vmcnt drain) so prefetches survive.
#define SCAN_T 1024

__global__ __launch_bounds__(512, 2) void k_scan_reg(
    const f16* __restrict__ xwp,   // packed xw (see k_gemm OUT==2)
    const f16* __restrict__ Wf,    // frag-packed [32][16][4][16][8]
    f16* __restrict__ hs,          // [64][1024][512] linear f16 (out)
    float* __restrict__ h_last) {  // [64][512] f32 (out)
  const int tid = threadIdx.x;
  const int w = tid >> 6, l = tid & 63;
  const int q = l >> 4, c = l & 15;
  const int set = blockIdx.x;
  const int b0 = set * 16;

  __shared__ __align__(16) f16 wlds[8][16][4][16][8];  // 128 KiB: cb 16..23
  __shared__ __align__(16) f16 hfrag[16][4][16][8];    // 16 KiB: h in frag layout

  const f16x8* WfB = (const f16x8*)Wf;
  const int cbs[4] = {w, 8 + w, 16 + w, 24 + w};

  // register-resident W frags (cb w and 8+w): 128 VGPR
  f16x8 wb0[16], wb1[16];
#pragma unroll
  for (int kt = 0; kt < 16; ++kt) {
    wb0[kt] = WfB[((w * 16 + kt) * 4 + q) * 16 + c];
    wb1[kt] = WfB[(((8 + w) * 16 + kt) * 4 + q) * 16 + c];
  }

  // stage LDS-resident W (cb 16..23): 8192 16B blocks, async
  {
    f16* dst0 = &wlds[0][0][0][0][0];
#pragma unroll
    for (int k = 0; k < 16; ++k) {
      int i = tid + k * 512;
      gll16(WfB + 16 * 1024 + i, dst0 + (size_t)(k * 512 + w * 64) * 8);
#if !USE_GLL
      ((f16x8*)dst0)[i] = WfB[16 * 1024 + i];
#endif
    }
  }
  // zero hfrag (h0 = 0)
  {
    uint4* hz = (uint4*)&hfrag[0][0][0][0];
    for (int i = tid; i < 1024; i += 512) hz[i] = make_uint4(0u, 0u, 0u, 0u);
  }

  // stream pointer for cb 24+w; frag kt at sp[kt*64]
  const f16x8* sp = WfB + (size_t)(24 + w) * 1024 + q * 16 + c;

  // packed-xw lane base (elements); j stride 256, tq stride 32768
  const f16* xwbase =
      xwp + (((((size_t)set * 256 * 8 + (size_t)w) * 4 + q) * 4 + 0) * 16 + c) * 16;

  // hs bases per j (element ptr incl. lane col offset c)
  f16* hsb[4];
#pragma unroll
  for (int j = 0; j < 4; ++j)
    hsb[j] = hs + (size_t)(b0 + q * 4 + j) * SCAN_T * 512 + c;

  // hoisted hfrag write pointers (row j=0); row stride 8 f16
  f16* hw[4];
#pragma unroll
  for (int i = 0; i < 4; ++i) {
    int k = cbs[i] * 16 + c;
    hw[i] = &hfrag[k >> 5][(k >> 3) & 3][q * 4][k & 7];
  }

  // prologue prefetch: xv for tq=0, stream slots kt=0..3
  f16x8 xv[4][2];
#pragma unroll
  for (int j = 0; j < 4; ++j) {
    xv[j][0] = __builtin_nontemporal_load((const f16x8*)(xwbase + j * 256));
    xv[j][1] = __builtin_nontemporal_load((const f16x8*)(xwbase + j * 256 + 8));
  }
  f16x8 sb[4];
#pragma unroll
  for (int kk = 0; kk < 4; ++kk) sb[kk] = sp[kk * 64];

  __syncthreads();  // full sync once: wlds/hfrag staged (drains gll vmcnt too)

  for (int tq = 0; tq < 256; ++tq) {
#pragma unroll
    for (int ts = 0; ts < 4; ++ts) {
      const int t = tq * 4 + ts;
      f32x4 zero4 = {0.f, 0.f, 0.f, 0.f};
      f32x4 acc[4] = {zero4, zero4, zero4, zero4};
#pragma unroll
      for (int kt = 0; kt < 16; ++kt) {
        f16x8 af = *(const f16x8*)&hfrag[kt][q][c][0];
        f16x8 wl = *(const f16x8*)&wlds[w][kt][q][c][0];
        f16x8 scur = sb[kt & 3];
        sb[kt & 3] = sp[((kt + 4) & 15) * 64];  // wraps into next step's kt 0..3
        acc[0] = __builtin_amdgcn_mfma_f32_16x16x32_f16(af, wb0[kt], acc[0], 0, 0, 0);
        acc[1] = __builtin_amdgcn_mfma_f32_16x16x32_f16(af, wb1[kt], acc[1], 0, 0, 0);
        acc[2] = __builtin_amdgcn_mfma_f32_16x16x32_f16(af, wl, acc[2], 0, 0, 0);
        acc[3] = __builtin_amdgcn_mfma_f32_16x16x32_f16(af, scur, acc[3], 0, 0, 0);
      }
      wg_sync_lds();  // all hfrag reads of h(t) done

      // extract z = acc + xw BEFORE reloading xv (WAR)
      float z[4][4];
#pragma unroll
      for (int i2 = 0; i2 < 4; ++i2)
#pragma unroll
        for (int j = 0; j < 4; ++j)
          z[i2][j] = acc[i2][j] + ((i2 < 2) ? (float)xv[j][0][i2 * 4 + ts]
                                            : (float)xv[j][1][(i2 - 2) * 4 + ts]);
      if (ts == 3) {  // prefetch next tq's xw (consumed ~a full step later)
        const int tqn = (tq < 255) ? tq + 1 : 255;
        const f16* pnx = xwbase + (size_t)tqn * 32768;
#pragma unroll
        for (int j = 0; j < 4; ++j) {
          xv[j][0] = __builtin_nontemporal_load((const f16x8*)(pnx + j * 256));
          xv[j][1] = __builtin_nontemporal_load((const f16x8*)(pnx + j * 256 + 8));
        }
      }

#pragma unroll
      for (int i2 = 0; i2 < 4; ++i2)
#pragma unroll
        for (int j = 0; j < 4; ++j) {
          float hv = tanh_fast(z[i2][j]);
          hw[i2][j * 8] = (f16)hv;  // h(t+1) frag write
          __builtin_nontemporal_store((f16)hv, hsb[j] + (size_t)t * 512 + cbs[i2] * 16);
          if (ts == 3 && tq == 255)
            h_last[(size_t)(b0 + q * 4 + j) * 512 + cbs[i2] * 16 + c] = hv;
        }
      wg_sync_lds();  // h(t+1) visible
    }
  }
}

// ---------------------------------------------------------------------------
extern "C" void kernel_launch(void* const* d_in, const int* in_sizes, int n_in,
                              void* d_out, int out_size, void* d_ws, size_t ws_size,
                              hipStream_t stream) {
  const float* x    = (const float*)d_in[0];  // [64][1024][512]
  const float* W_xh = (const float*)d_in[1];  // [512][512]
  const float* b_h  = (const float*)d_in[2];  // [512]
  const float* W_hh = (const float*)d_in[3];  // [512][512]
  const float* W_o  = (const float*)d_in[4];  // [512][512]
  const float* b_o  = (const float*)d_in[5];  // [512]
  float* out = (float*)d_out;                 // logits [64][1024][512] ++ h_last [64][512]

  const size_t XWN = (size_t)64 * 1024 * 512;
  char* ws = (char*)d_ws;
  f16* xf   = (f16*)(ws);                       // 64 MiB (x f16 -> later hs)
  f16* xwp  = (f16*)(ws + XWN * 2);             // 64 MiB (packed xW f16)
  f16* WxhT = (f16*)(ws + XWN * 4);             // 512 KiB
  f16* WoT  = (f16*)(ws + XWN * 4 + 524288);    // 512 KiB
  f16* Wf   = (f16*)(ws + XWN * 4 + 1048576);   // 512 KiB (frag-packed W_hh)

  // prep: converts + transposes + frag-pack
  k_cvt_f16<<<4096, 256, 0, stream>>>(x, xf, (int)(XWN / 4));
  k_transpose_cvt<<<256, 256, 0, stream>>>(W_xh, WxhT);
  k_transpose_cvt<<<256, 256, 0, stream>>>(W_o, WoT);
  k_packW<<<128, 256, 0, stream>>>(W_hh, Wf);

  // xW = x @ W_xh + b_h, written directly in scan-packed layout
  k_gemm<2><<<2048, 256, 0, stream>>>(xf, WxhT, b_h, xwp, 65536, 512, 512);

  // sequential scan: 4 self-contained WGs, no cross-WG communication
  k_scan_reg<<<4, 512, 0, stream>>>(xwp, Wf, xf /*hs*/, out + XWN);

  // logits = hs @ W_o + b_o   (f32 out)
  k_gemm<0><<<2048, 256, 0, stream>>>(xf, WoT, b_o, out, 65536, 512, 512);
}